// Round 17
// baseline (300.675 us; speedup 1.0000x reference)
//
#include <hip/hip_runtime.h>
#include <hip/hip_bf16.h>
#include <math.h>

// ISTFT as split-K bf16 GEMM: out[b][r*256+j] = sum_{d=0..3} frames[r-3+d] . Bseg_d[.][j]
//   Bseg_d[2f][j]   =  wR(f) cos(2pi n f/1024) * syn[n]/1024,  n = (3-d)*256 + j
//   Bseg_d[2f+1][j] = -2     sin(2pi n f/1024) * syn[n]/1024   (wR=1 at f=0,512)
// R17: 4 waves/block = 4 segments of ONE 64x64 output tile; per-wave K=1056
//   (33 steps of BK=32), wave-private single-buffered LDS staging (8 KB each),
//   barrier-free K-loop; then block-internal LDS reduction (ds_write + ds_add)
//   and plain float4 stores. Boundary frames: clamped A-reads + epilogue
//   masking (t outside [0,2048) => contribution zeroed) -> NO pad rows; Ab is
//   exactly R3's proven [32768][1056] layout (ws use = 71,368,704 B, verified).
//   Wave-tiles: 2112 blocks x 4 = 8448 (4x R16) -> ~16 resident waves/CU.

#define BATCH  16
#define TFR    2048
#define HOP    256
#define OUTLEN 525056
#define RROWS  2051                   // output rows per batch
#define KPAD   1056                   // padded K per segment (33*32)
#define KVAL   1026
#define BK     32
#define NKT    (KPAD / BK)            // 33
#define MTB    33                     // 64-row tiles per batch (33*64 = 2112 >= 2051)
#define CHPR   (KPAD / 8)             // 132

typedef __attribute__((ext_vector_type(4))) float f32x4;
typedef __attribute__((ext_vector_type(8))) short bf16x8;

__device__ __forceinline__ void load_lds16(const void* g, void* l)
{
    __builtin_amdgcn_global_load_lds((const __attribute__((address_space(1))) void*)g,
                                     (__attribute__((address_space(3))) void*)l,
                                     16, 0, 0);
}

#define STEP 6.13592315e-3f           // 2*pi/1024

// ---- B tables: Bg[d][j][k], k contiguous (row stride KPAD) ----
__global__ __launch_bounds__(256)
void build_B(__hip_bfloat16* __restrict__ Bg)
{
    __shared__ float cosT[1024];
    __shared__ float sinT[1024];
    const int g = blockIdx.x;                 // 0..1023 = d*256 + j
    const int d = g >> 8;
    const int j = g & 255;
    const int n = (3 - d) * 256 + j;          // 0..1023
    for (int i = threadIdx.x; i < 1024; i += 256) {
        float s, c;
        sincosf((float)i * STEP, &s, &c);
        cosT[i] = c; sinT[i] = s;
    }
    __syncthreads();

    const float syn = (0.5f - 0.5f * cosT[n]) * 0.8660254f * (1.0f / 1024.0f);
    for (int k = threadIdx.x; k < KPAD; k += 256) {
        float val = 0.f;
        if (k < KVAL) {
            const int f   = k >> 1;
            const int idx = (n * f) & 1023;
            if ((k & 1) == 0) {
                const float wr = (f == 0 || f == 512) ? 1.f : 2.f;
                val = wr * cosT[idx] * syn;
            } else {
                val = -2.f * sinT[idx] * syn;
            }
        }
        Bg[(size_t)g * KPAD + k] = __float2bfloat16(val);
    }
}

// ---- convert: stfts fp32 [32768][1026] -> Ab bf16 [32768][1056] (R3-proven) ----
__global__ __launch_bounds__(256)
void convert_A(const float* __restrict__ A, __hip_bfloat16* __restrict__ Ab)
{
    const int idx = blockIdx.x * 256 + threadIdx.x;
    if (idx >= BATCH * TFR * CHPR) return;
    const int m  = idx / CHPR;
    const int k8 = (idx - m * CHPR) * 8;

    const float* src = A + (size_t)m * KVAL + k8;
    union { bf16x8 v; __hip_bfloat162 h[4]; } u;
    #pragma unroll
    for (int j = 0; j < 8; j += 2) {
        float2 p = make_float2(0.f, 0.f);
        if (k8 + j < KVAL)                    // KVAL even: pair all-or-nothing
            p = *reinterpret_cast<const float2*>(src + j);
        u.h[j >> 1] = __float22bfloat162_rn(p);
    }
    *reinterpret_cast<bf16x8*>(Ab + (size_t)m * KPAD + k8) = u.v;
}

// ---- GEMM: 4 waves = 4 segments of one 64x64 tile + LDS reduce ----
__global__ __launch_bounds__(256)
void istft_gemm6(const __hip_bfloat16* __restrict__ Ab,
                 const __hip_bfloat16* __restrict__ Bg,
                 float* __restrict__ out)
{
    __shared__ __align__(16) char pool[32768];   // 4 x (A 4KB + B 4KB); reused as 16KB reduce

    const int tid  = threadIdx.x;
    const int lane = tid & 63;
    const int d    = tid >> 6;                   // wave index = segment

    // XCD remap: 2112 blocks = 8 XCDs x (66 M-tiles x 4 N-tiles), nt fast
    const int wg   = blockIdx.x;
    const int xcd  = wg & 7;
    const int slot = wg >> 3;                    // 0..263
    const int mtg  = xcd * 66 + (slot >> 2);     // 0..527
    const int nt   = slot & 3;
    const int b    = mtg / MTB;
    const int rt   = (mtg - b * MTB) * 64;
    const int n0   = nt * 64;

    __hip_bfloat16* Asl = (__hip_bfloat16*)(pool + d * 8192);
    __hip_bfloat16* Bsl = (__hip_bfloat16*)(pool + d * 8192 + 4096);

    const int srow = lane >> 2;                  // 0..15
    const int scol = (lane & 3) * 8;

    // staging pointers (i = 16-row groups); A frame index clamped to [0,2047]
    const __hip_bfloat16* gA[4];
    const __hip_bfloat16* gB[4];
    #pragma unroll
    for (int i = 0; i < 4; ++i) {
        int t = rt - 3 + d + i * 16 + srow;
        t = t < 0 ? 0 : (t > TFR - 1 ? TFR - 1 : t);
        gA[i] = Ab + ((size_t)b * TFR + t) * KPAD + scol;
        gB[i] = Bg + (size_t)(d * 256 + n0 + i * 16 + srow) * KPAD + scol;
    }

    const int fr = lane & 15;
    const int fk = (lane >> 4) * 8;

    f32x4 acc[4][4] = {};

#define STAGE(kt)                                                              \
    {                                                                          \
        const int _ko = (kt) * BK;                                             \
        _Pragma("unroll")                                                      \
        for (int _i = 0; _i < 4; ++_i) {                                       \
            load_lds16(gA[_i] + _ko, Asl + _i * 512 + lane * 8);               \
            load_lds16(gB[_i] + _ko, Bsl + _i * 512 + lane * 8);               \
        }                                                                      \
    }

    STAGE(0)
    for (int kt = 0; kt < NKT; ++kt) {
        asm volatile("s_waitcnt vmcnt(0)" ::: "memory");     // this kt's 8 loads done
        __builtin_amdgcn_sched_barrier(0);

        bf16x8 a[4], bv[4];
        #pragma unroll
        for (int mi = 0; mi < 4; ++mi)
            a[mi] = *reinterpret_cast<const bf16x8*>(&Asl[(mi * 16 + fr) * BK + fk]);
        #pragma unroll
        for (int ni = 0; ni < 4; ++ni)
            bv[ni] = *reinterpret_cast<const bf16x8*>(&Bsl[(ni * 16 + fr) * BK + fk]);

        asm volatile("s_waitcnt lgkmcnt(0)" ::: "memory");   // frags in regs before overwrite
        __builtin_amdgcn_sched_barrier(0);

        if (kt + 1 < NKT) STAGE(kt + 1)                       // hidden under MFMA

        #pragma unroll
        for (int mi = 0; mi < 4; ++mi)
            #pragma unroll
            for (int ni = 0; ni < 4; ++ni)
                acc[mi][ni] = __builtin_amdgcn_mfma_f32_16x16x32_bf16(
                    a[mi], bv[ni], acc[mi][ni], 0, 0, 0);
    }
#undef STAGE

    // ---- block reduction: wave0 writes (masked), waves 1-3 ds_add (masked) ----
    float* red = (float*)pool;                   // 64x64 fp32 = 16 KB (aliases staging)
    const int cr = (lane >> 4) * 4;
    const int cc = lane & 15;

    __syncthreads();                             // all staging reads complete

    if (d == 0) {
        #pragma unroll
        for (int mi = 0; mi < 4; ++mi)
            #pragma unroll
            for (int ni = 0; ni < 4; ++ni)
                #pragma unroll
                for (int j = 0; j < 4; ++j) {
                    const int row = mi * 16 + cr + j;
                    const int t   = rt + row - 3;             // d = 0
                    const float v = (t >= 0 && t < TFR) ? acc[mi][ni][j] : 0.f;
                    red[row * 64 + ni * 16 + cc] = v;
                }
    }
    __syncthreads();
    if (d != 0) {
        #pragma unroll
        for (int mi = 0; mi < 4; ++mi)
            #pragma unroll
            for (int ni = 0; ni < 4; ++ni)
                #pragma unroll
                for (int j = 0; j < 4; ++j) {
                    const int row = mi * 16 + cr + j;
                    const int t   = rt + row - 3 + d;
                    if (t >= 0 && t < TFR)
                        atomicAdd(&red[row * 64 + ni * 16 + cc], acc[mi][ni][j]);
                }
    }
    __syncthreads();

    // ---- cooperative store (each out element written exactly once) ----
    float* og = out + (size_t)b * OUTLEN;
    for (int idx = tid; idx < 64 * 16; idx += 256) {
        const int row = idx >> 4;
        const int c4  = (idx & 15) * 4;
        const int r   = rt + row;
        if (r < RROWS) {
            const float4 v = *reinterpret_cast<const float4*>(&red[row * 64 + c4]);
            *reinterpret_cast<float4*>(&og[(size_t)r * 256 + n0 + c4]) = v;
        }
    }
}

extern "C" void kernel_launch(void* const* d_in, const int* in_sizes, int n_in,
                              void* d_out, int out_size, void* d_ws, size_t ws_size,
                              hipStream_t stream)
{
    const float* A = reinterpret_cast<const float*>(d_in[0]);
    float* out = reinterpret_cast<float*>(d_out);

    const size_t abBytes = (size_t)BATCH * TFR * KPAD * sizeof(__hip_bfloat16); // 69.21 MB
    __hip_bfloat16* Ab = reinterpret_cast<__hip_bfloat16*>(d_ws);
    __hip_bfloat16* Bg = reinterpret_cast<__hip_bfloat16*>((char*)d_ws + abBytes); // +2.16 MB

    build_B<<<dim3(1024), dim3(256), 0, stream>>>(Bg);

    const int nChunks = BATCH * TFR * CHPR;                  // 4,325,376
    convert_A<<<dim3((nChunks + 255) / 256), dim3(256), 0, stream>>>(A, Ab);

    istft_gemm6<<<dim3(BATCH * MTB * 4), dim3(256), 0, stream>>>(Ab, Bg, out);
}

// Round 18
// 253.277 us; speedup vs baseline: 1.1871x; 1.1871x over previous
//
#include <hip/hip_runtime.h>
#include <hip/hip_bf16.h>
#include <math.h>

// ISTFT as atomic-free bf16 GEMM over an overlapped row view (R13 formulation):
//   out[b][r*256+j] = A_view[b,r] . Bstack[.][j],  A_view[b,r] = 4160 contiguous
//   bf16 at Ab + (b*PBR + r)*FSTR  (padded frames; boundary rows are zeros).
// R18: A-READ-ONCE tiling. R13-R17 all moved ~1.2-2.2 GB through L2/L3 because
//   each A panel was re-read per N-tile; all variants pinned at ~195 us (cache-BW
//   wall). Here each block owns 64 rows x FULL N=256: A streamed exactly once
//   (69 MB total), B (2.13 MB) is the only re-read operand and is L2-resident
//   per XCD. 528 blocks = 8 XCDs x 66 (exact remap); 4 waves = 4 N-quarters
//   share the staged A tile; m97 2-barrier loop, NKT=130.

#define BATCH  16
#define TFR    2048
#define HOP    256
#define OUTLEN 525056
#define RROWS  2051                   // output rows per batch (525056/256)
#define PBR    2054                   // padded rows per batch: 3 + 2048 + 3
#define FSTR   1040                   // bf16 elems per padded frame row
#define KTOT   (4 * FSTR)             // 4160
#define BK     32
#define NKT    (KTOT / BK)            // 130
#define KVAL   1026                   // valid elems per frame row
#define MTB    33                     // 64-row M-tiles per batch (33*64 >= 2051)
#define MTOT   (BATCH * MTB)          // 528 = 8 XCDs * 66
#define TOTROW (BATCH * PBR + 128)    // 32992 incl. slack rows (OOB-read guard)
#define CHPR   (FSTR / 8)             // 130

typedef __attribute__((ext_vector_type(4))) float f32x4;
typedef __attribute__((ext_vector_type(8))) short bf16x8;

__device__ __forceinline__ void load_lds16(const void* g, void* l)
{
    __builtin_amdgcn_global_load_lds((const __attribute__((address_space(1))) void*)g,
                                     (__attribute__((address_space(3))) void*)l,
                                     16, 0, 0);
}

#define STEP 6.13592315e-3f           // 2*pi/1024

// ---- Bstack, stored transposed: Bg[j][k], k contiguous (row stride KTOT) ----
__global__ __launch_bounds__(256)
void build_B(__hip_bfloat16* __restrict__ Bg)
{
    __shared__ float cosT[1024];
    __shared__ float sinT[1024];
    const int j = blockIdx.x;
    for (int i = threadIdx.x; i < 1024; i += 256) {
        float s, c;
        sincosf((float)i * STEP, &s, &c);
        cosT[i] = c; sinT[i] = s;
    }
    __syncthreads();

    for (int k = threadIdx.x; k < KTOT; k += 256) {
        const int d  = k / FSTR;
        const int kk = k - d * FSTR;
        float val = 0.f;
        if (kk < KVAL) {
            const int   f   = kk >> 1;
            const int   n   = 768 - 256 * d + j;              // 0..1023
            const float syn = (0.5f - 0.5f * cosT[n]) * 0.8660254f * (1.0f / 1024.0f);
            const int   idx = (n * f) & 1023;
            if ((kk & 1) == 0) {
                const float wr = (f == 0 || f == 512) ? 1.f : 2.f;
                val = wr * cosT[idx] * syn;
            } else {
                val = -2.f * sinT[idx] * syn;
            }
        }
        Bg[(size_t)j * KTOT + k] = __float2bfloat16(val);
    }
}

// ---- convert: stfts fp32 -> Ab bf16 padded layout (R13-verified) ----
__global__ __launch_bounds__(256)
void convert_A(const float* __restrict__ A, __hip_bfloat16* __restrict__ Ab)
{
    const int idx = blockIdx.x * 256 + threadIdx.x;
    if (idx >= TOTROW * CHPR) return;
    const int row = idx / CHPR;
    const int c8  = (idx - row * CHPR) * 8;

    const int b  = row / PBR;                 // >=16 -> slack
    const int rr = row - b * PBR;
    const bool valid = (b < BATCH) && (rr >= 3) && (rr < 3 + TFR);

    union { bf16x8 v; __hip_bfloat162 h[4]; } u;
    if (valid) {
        const int t = rr - 3;
        const float* src = A + (size_t)(b * TFR + t) * KVAL + c8;
        #pragma unroll
        for (int j = 0; j < 8; j += 2) {
            float2 p = make_float2(0.f, 0.f);
            if (c8 + j < KVAL)                // KVAL even: pair all-or-nothing
                p = *reinterpret_cast<const float2*>(src + j);
            u.h[j >> 1] = __float22bfloat162_rn(p);
        }
    } else {
        #pragma unroll
        for (int j = 0; j < 4; ++j) u.h[j] = __float22bfloat162_rn(make_float2(0.f, 0.f));
    }
    *reinterpret_cast<bf16x8*>(Ab + (size_t)row * FSTR + c8) = u.v;
}

// ---- GEMM: 64(M) x 256(N=full) tile, 4 waves = 4 N-quarters, A staged once ----
__global__ __launch_bounds__(256)
void istft_gemm7(const __hip_bfloat16* __restrict__ Ab,
                 const __hip_bfloat16* __restrict__ Bg,
                 float* __restrict__ out)
{
    __shared__ __hip_bfloat16 Asl[64 * BK];    // 4 KB, shared by all 4 waves
    __shared__ __hip_bfloat16 Bsl[256 * BK];   // 16 KB (wave w uses rows w*64..)

    const int tid  = threadIdx.x;
    const int lane = tid & 63;
    const int wave = tid >> 6;                 // N-quarter: cols wave*64..+63

    // XCD remap: 528 blocks = 8 XCDs x 66 M-tiles (adjacent tiles same XCD)
    const int wg  = blockIdx.x;
    const int mtg = (wg & 7) * 66 + (wg >> 3); // 0..527
    const int b   = mtg / MTB;
    const int rt  = (mtg - b * MTB) * 64;

    const int srow = tid >> 2;                 // 0..63
    const int scol = (tid & 3) * 8;

    const __hip_bfloat16* gA = Ab + ((size_t)b * PBR + rt + srow) * FSTR + scol;
    const __hip_bfloat16* gB0 = Bg + (size_t)srow * KTOT + scol;          // rows 0..63
    const __hip_bfloat16* gB1 = Bg + (size_t)(64 + srow) * KTOT + scol;
    const __hip_bfloat16* gB2 = Bg + (size_t)(128 + srow) * KTOT + scol;
    const __hip_bfloat16* gB3 = Bg + (size_t)(192 + srow) * KTOT + scol;

    const int fr = lane & 15;
    const int fk = (lane >> 4) * 8;

    f32x4 acc[4][4] = {};

    for (int kt = 0; kt < NKT; ++kt) {
        const int ko = kt * BK;
        load_lds16(gA + ko, Asl + tid * 8);
        load_lds16(gB0 + ko, Bsl + tid * 8);
        load_lds16(gB1 + ko, Bsl + 2048 + tid * 8);
        load_lds16(gB2 + ko, Bsl + 4096 + tid * 8);
        load_lds16(gB3 + ko, Bsl + 6144 + tid * 8);
        __syncthreads();

        bf16x8 a[4], bv[4];
        #pragma unroll
        for (int mi = 0; mi < 4; ++mi)
            a[mi] = *reinterpret_cast<const bf16x8*>(&Asl[(mi * 16 + fr) * BK + fk]);
        #pragma unroll
        for (int ni = 0; ni < 4; ++ni)
            bv[ni] = *reinterpret_cast<const bf16x8*>(&Bsl[(wave * 64 + ni * 16 + fr) * BK + fk]);

        #pragma unroll
        for (int mi = 0; mi < 4; ++mi)
            #pragma unroll
            for (int ni = 0; ni < 4; ++ni)
                acc[mi][ni] = __builtin_amdgcn_mfma_f32_16x16x32_bf16(
                    a[mi], bv[ni], acc[mi][ni], 0, 0, 0);

        __syncthreads();
    }

    // epilogue: C/D layout col = lane&15, row = (lane>>4)*4 + j; plain stores
    const int cr = (lane >> 4) * 4;
    const int cc = lane & 15;
    #pragma unroll
    for (int mi = 0; mi < 4; ++mi) {
        #pragma unroll
        for (int ni = 0; ni < 4; ++ni) {
            const int col = wave * 64 + ni * 16 + cc;
            #pragma unroll
            for (int j = 0; j < 4; ++j) {
                const int r = rt + mi * 16 + cr + j;
                if (r < RROWS)
                    out[(size_t)b * OUTLEN + (size_t)r * 256 + col] = acc[mi][ni][j];
            }
        }
    }
}

extern "C" void kernel_launch(void* const* d_in, const int* in_sizes, int n_in,
                              void* d_out, int out_size, void* d_ws, size_t ws_size,
                              hipStream_t stream)
{
    const float* A = reinterpret_cast<const float*>(d_in[0]);
    float* out = reinterpret_cast<float*>(d_out);

    const size_t abBytes = (size_t)TOTROW * FSTR * sizeof(__hip_bfloat16); // 68.62 MB
    __hip_bfloat16* Ab = reinterpret_cast<__hip_bfloat16*>(d_ws);
    __hip_bfloat16* Bg = reinterpret_cast<__hip_bfloat16*>((char*)d_ws + abBytes); // +2.13 MB

    build_B<<<dim3(256), dim3(256), 0, stream>>>(Bg);

    const int nChunks = TOTROW * CHPR;                       // 4,288,960
    convert_A<<<dim3((nChunks + 255) / 256), dim3(256), 0, stream>>>(A, Ab);

    istft_gemm7<<<dim3(MTOT), dim3(256), 0, stream>>>(Ab, Bg, out);
}